// Round 3
// baseline (625.062 us; speedup 1.0000x reference)
//
#include <hip/hip_runtime.h>

// 0.8*dice_loss(pred,target) + 0.2*soft_cldice_loss(pred,target)
// pred/target: (64,1,512,512) fp32 -> 1 fp32 scalar.
//
// soft_skeletonize = 10x: x = relu(x - (dil3(ero3(x)) - ero3(x)))
//   (inner relu dropped: dil3 includes self => dil3(e) >= e; verified R10 pass)
//   ero3 = 3x3 min-pool, x OOB -> +inf; dil3 = 3x3 max-pool, e OOB -> -inf
//
// R11: TEMPORAL BLOCKING. R9 (reg prefetch) and R10 (LDS queue + counted
// vmcnt) were both neutral -> the 5-pass structure is pinned at ~3 TB/s and
// 1.44 GB of traffic IS the runtime. This round eliminates the traffic:
// one mega-kernel holds an 80-row tile in 160 KB LDS and runs all 10
// skeletonize iterations in-LDS (20-row halo erodes 2 rows/iter; 80-row
// tile -> exactly 40 correct owned rows). Per iteration: each of 16 waves
// computes its 5 rows into registers (read-only), barrier, writes back,
// barrier -> race-free by construction. Rows outside the shrinking valid
// window compute garbage that is never read; image-OOB rows are +inf via
// the row loader (independent of tile contents), so edge semantics hold
// every iteration. Dice fused at load (raw), pairing fused at end (skel).
// HBM: ~0.4 GB total vs 1.44 GB. 128KB-LDS fallback template included.
//
// Harness rules learned: d_ws too small -> state in __device__ BSS;
// never pass __device__ symbols as host-side kernel args; plain
// __launch_bounds__ (tight second arg spilled in R7).

#define H 512
#define W 512
#define W4 (W / 4)
#define NIMG 64
#define IMG_ELEMS (H * W)
#define NDICE_SLOTS 64
#define ITERS 10

__device__ float g_acc[NIMG * 4];                 // per-image pairing sums
__device__ float g_dice[NDICE_SLOTS * 16];        // spread dice accumulators

struct F8 { float4 a, b; };          // 8 consecutive columns per lane

__device__ __forceinline__ F8 f8fill(float v) {
  F8 r; r.a = make_float4(v, v, v, v); r.b = r.a; return r;
}
__device__ __forceinline__ F8 f8min(const F8& x, const F8& y) {
  F8 r;
  r.a.x = fminf(x.a.x, y.a.x); r.a.y = fminf(x.a.y, y.a.y);
  r.a.z = fminf(x.a.z, y.a.z); r.a.w = fminf(x.a.w, y.a.w);
  r.b.x = fminf(x.b.x, y.b.x); r.b.y = fminf(x.b.y, y.b.y);
  r.b.z = fminf(x.b.z, y.b.z); r.b.w = fminf(x.b.w, y.b.w);
  return r;
}
__device__ __forceinline__ F8 f8max(const F8& x, const F8& y) {
  F8 r;
  r.a.x = fmaxf(x.a.x, y.a.x); r.a.y = fmaxf(x.a.y, y.a.y);
  r.a.z = fmaxf(x.a.z, y.a.z); r.a.w = fmaxf(x.a.w, y.a.w);
  r.b.x = fmaxf(x.b.x, y.b.x); r.b.y = fmaxf(x.b.y, y.b.y);
  r.b.z = fmaxf(x.b.z, y.b.z); r.b.w = fmaxf(x.b.w, y.b.w);
  return r;
}
// horizontal 3-tap min; L/R image edges see +inf
__device__ __forceinline__ F8 ero8(const F8& v, int lane) {
  float L = __shfl_up(v.b.w, 1, 64);
  if (lane == 0) L = __builtin_inff();
  float R = __shfl_down(v.a.x, 1, 64);
  if (lane == 63) R = __builtin_inff();
  F8 e;
  e.a.x = fminf(L,     fminf(v.a.x, v.a.y));
  e.a.y = fminf(v.a.x, fminf(v.a.y, v.a.z));
  e.a.z = fminf(v.a.y, fminf(v.a.z, v.a.w));
  e.a.w = fminf(v.a.z, fminf(v.a.w, v.b.x));
  e.b.x = fminf(v.a.w, fminf(v.b.x, v.b.y));
  e.b.y = fminf(v.b.x, fminf(v.b.y, v.b.z));
  e.b.z = fminf(v.b.y, fminf(v.b.z, v.b.w));
  e.b.w = fminf(v.b.z, fminf(v.b.w, R));
  return e;
}
// horizontal 3-tap max; edges see -inf
__device__ __forceinline__ F8 dil8(const F8& v, int lane) {
  float L = __shfl_up(v.b.w, 1, 64);
  if (lane == 0) L = -__builtin_inff();
  float R = __shfl_down(v.a.x, 1, 64);
  if (lane == 63) R = -__builtin_inff();
  F8 d;
  d.a.x = fmaxf(L,     fmaxf(v.a.x, v.a.y));
  d.a.y = fmaxf(v.a.x, fmaxf(v.a.y, v.a.z));
  d.a.z = fmaxf(v.a.y, fmaxf(v.a.z, v.a.w));
  d.a.w = fmaxf(v.a.z, fmaxf(v.a.w, v.b.x));
  d.b.x = fmaxf(v.a.w, fmaxf(v.b.x, v.b.y));
  d.b.y = fmaxf(v.b.x, fmaxf(v.b.y, v.b.z));
  d.b.z = fmaxf(v.b.y, fmaxf(v.b.z, v.b.w));
  d.b.w = fmaxf(v.b.z, fmaxf(v.b.w, R));
  return d;
}
__device__ __forceinline__ F8 f8sub(const F8& x, const F8& y) {
  F8 r;
  r.a.x = x.a.x - y.a.x; r.a.y = x.a.y - y.a.y;
  r.a.z = x.a.z - y.a.z; r.a.w = x.a.w - y.a.w;
  r.b.x = x.b.x - y.b.x; r.b.y = x.b.y - y.b.y;
  r.b.z = x.b.z - y.b.z; r.b.w = x.b.w - y.b.w;
  return r;
}
__device__ __forceinline__ F8 f8relu_sub(const F8& x, const F8& y) {
  F8 r;
  r.a.x = fmaxf(x.a.x - y.a.x, 0.f); r.a.y = fmaxf(x.a.y - y.a.y, 0.f);
  r.a.z = fmaxf(x.a.z - y.a.z, 0.f); r.a.w = fmaxf(x.a.w - y.a.w, 0.f);
  r.b.x = fmaxf(x.b.x - y.b.x, 0.f); r.b.y = fmaxf(x.b.y - y.b.y, 0.f);
  r.b.z = fmaxf(x.b.z - y.b.z, 0.f); r.b.w = fmaxf(x.b.w - y.b.w, 0.f);
  return r;
}

// TROWS rows in LDS; RR = TROWS - 2*HALO owned rows; HALO = 2 rows/iter * 10.
// Block = 1024 threads = 16 waves; wave j owns CH = TROWS/16 tile rows.
template <int TROWS, int RR>
__global__ __launch_bounds__(1024) void mega(
    const float* __restrict__ pred, const float* __restrict__ target) {
  extern __shared__ float tile[];                  // TROWS * W floats
  constexpr int NSTRIP = (H + RR - 1) / RR;
  constexpr int HALO = (TROWS - RR) / 2;           // 20
  constexpr int CH = TROWS / 16;                   // rows per wave
  const float PINF = __builtin_inff();

  const int u     = blockIdx.x / NSTRIP;           // 0..127 (chain element)
  const int strip = blockIdx.x % NSTRIP;
  const int g0    = strip * RR;
  const int nown  = min(H - g0, RR);               // owned rows (last strip ragged)
  const bool isPred = (u < NIMG);
  const int img  = isPred ? u : u - NIMG;
  const float* src   = (isPred ? pred : target) + (size_t)img * IMG_ELEMS;
  const float* other = (isPred ? target : pred) + (size_t)img * IMG_ELEMS;

  const int tid  = threadIdx.x;
  const int lane = tid & 63;
  const int wave = tid >> 6;                       // 0..15
  const int gbase = g0 - HALO;                     // global row of tile row 0

  // ---- load tile (image rows [gbase, gbase+TROWS) clamped to [0,H)) ----
  {
    const float4* s4 = (const float4*)src;
    float4* t4 = (float4*)tile;
    for (int i = tid; i < TROWS * W4; i += 1024) {
      int gr = gbase + (i >> 7);                   // W4 == 128
      if (gr >= 0 && gr < H) t4[i] = s4[(size_t)gr * W4 + (i & 127)];
    }
  }
  __syncthreads();

  // ---- dice sums on raw data (owned rows only) ----
  {
    float a0 = 0.f, a1 = 0.f;
    const float4* o4 = (const float4*)(other + (size_t)g0 * W);
    const float4* x4 = (const float4*)(tile + (size_t)HALO * W);
    for (int i = tid; i < nown * W4; i += 1024) {
      float4 x = x4[i];
      if (isPred) {
        float4 t = o4[i];
        a0 += x.x * t.x + x.y * t.y + x.z * t.z + x.w * t.w;
        a1 += x.x + x.y + x.z + x.w;
      } else {
        a0 += x.x + x.y + x.z + x.w;               // target-sum role
      }
    }
    #pragma unroll
    for (int o = 32; o; o >>= 1) {
      a0 += __shfl_down(a0, o, 64);
      a1 += __shfl_down(a1, o, 64);
    }
    if (lane == 0) {
      float* slot = &g_dice[(blockIdx.x & (NDICE_SLOTS - 1)) * 16];
      if (isPred) { atomicAdd(slot + 0, a0); atomicAdd(slot + 1, a1); }
      else        { atomicAdd(slot + 2, a0); }
    }
  }

  // ---- 10 in-LDS skeletonize iterations ----
  const int tb = wave * CH;                        // first tile row of chunk
  auto ldrow = [&](int tr) -> F8 {
    int gr = gbase + tr;
    F8 v;
    if (gr >= 0 && gr < H) {
      // clamp LDS index: tr outside tile only happens for rows whose
      // outputs are outside the valid window (never read) -> any data ok
      int trc = tr < 0 ? 0 : (tr >= TROWS ? TROWS - 1 : tr);
      const float4* p = (const float4*)(tile + (size_t)trc * W);
      v.a = p[lane * 2]; v.b = p[lane * 2 + 1];
    } else {
      v = f8fill(PINF);                            // true image OOB: +inf
    }
    return v;
  };
  auto erow = [&](const F8& x0, const F8& x1, const F8& x2, int tr) -> F8 {
    F8 e = ero8(f8min(f8min(x0, x1), x2), lane);
    int gr = gbase + tr;
    if (gr < 0 || gr >= H) e = f8fill(-PINF);      // e OOB: -inf (dil pad)
    return e;
  };

  for (int k = 0; k < ITERS; ++k) {
    __syncthreads();                               // prior writes visible
    // read-only compute of CH rows into registers
    F8 xm = ldrow(tb - 2);
    F8 xc = ldrow(tb - 1);
    F8 xp = ldrow(tb);                             // x[tb]
    F8 eM = erow(xm, xc, xp, tb - 1);              // e[tb-1]
    F8 xq = ldrow(tb + 1);
    F8 eC = erow(xc, xp, xq, tb);                  // e[tb]
    F8 y[CH];
    #pragma unroll
    for (int i = 0; i < CH; ++i) {
      F8 xn = ldrow(tb + 2 + i);
      F8 eP = erow(xp, xq, xn, tb + 1 + i);        // e[tb+1+i]
      F8 d  = dil8(f8max(f8max(eM, eC), eP), lane);
      y[i]  = f8relu_sub(xp, f8sub(d, eC));        // relu(x - (dil - ero))
      xp = xq; xq = xn; eM = eC; eC = eP;
    }
    __syncthreads();                               // all reads done
    #pragma unroll
    for (int i = 0; i < CH; ++i) {
      float4* p = (float4*)(tile + (size_t)(tb + i) * W);
      p[lane * 2]     = y[i].a;
      p[lane * 2 + 1] = y[i].b;
    }
  }
  __syncthreads();

  // ---- pairing sums on skeleton (owned rows) ----
  {
    float b0 = 0.f, b1 = 0.f;
    const float4* o4 = (const float4*)(other + (size_t)g0 * W);
    const float4* x4 = (const float4*)(tile + (size_t)HALO * W);
    for (int i = tid; i < nown * W4; i += 1024) {
      float4 x = x4[i];
      float4 t = o4[i];
      b0 += x.x * t.x + x.y * t.y + x.z * t.z + x.w * t.w;
      b1 += x.x + x.y + x.z + x.w;
    }
    #pragma unroll
    for (int o = 32; o; o >>= 1) {
      b0 += __shfl_down(b0, o, 64);
      b1 += __shfl_down(b1, o, 64);
    }
    if (lane == 0) {
      const int base = img * 4 + (isPred ? 0 : 2);
      atomicAdd(&g_acc[base + 0], b0);             // sum(skel * other)
      atomicAdd(&g_acc[base + 1], b1);             // sum(skel)
    }
  }
}

__global__ void zero_acc() {
  for (int i = threadIdx.x; i < NIMG * 4; i += 256) g_acc[i] = 0.0f;
  for (int i = threadIdx.x; i < NDICE_SLOTS * 16; i += 256) g_dice[i] = 0.0f;
}

__global__ void final_kernel(float* __restrict__ out) {
  const int lane = threadIdx.x;  // 64 threads = 64 images / 64 dice slots
  float s1 = g_acc[lane * 4 + 0], s2 = g_acc[lane * 4 + 1];
  float s3 = g_acc[lane * 4 + 2], s4 = g_acc[lane * 4 + 3];
  float iflat = (s1 + 1.0f) / (s2 + 1.0f);
  float tflat = (s3 + 1.0f) / (s4 + 1.0f);
  float prod = iflat * tflat;
  float ssum = iflat + tflat;
  float d0 = g_dice[lane * 16 + 0];
  float d1 = g_dice[lane * 16 + 1];
  float d2 = g_dice[lane * 16 + 2];
  #pragma unroll
  for (int o = 32; o; o >>= 1) {
    prod += __shfl_down(prod, o, 64);
    ssum += __shfl_down(ssum, o, 64);
    d0   += __shfl_down(d0, o, 64);
    d1   += __shfl_down(d1, o, 64);
    d2   += __shfl_down(d2, o, 64);
  }
  if (lane == 0) {
    float cldice = 1.0f - 2.0f * prod / ssum;
    float dice = 1.0f - (2.0f * d0 + 1e-6f) / (d1 + d2 + 1e-6f);
    out[0] = 0.8f * dice + 0.2f * cldice;
  }
}

extern "C" void kernel_launch(void* const* d_in, const int* in_sizes, int n_in,
                              void* d_out, int out_size, void* d_ws, size_t ws_size,
                              hipStream_t stream) {
  const float* pred   = (const float*)d_in[0];
  const float* target = (const float*)d_in[1];
  float* out = (float*)d_out;
  (void)d_ws; (void)ws_size;

  // 160 KB LDS variant (80-row tile, R=40) with 128 KB fallback (64-row, R=24).
  static int use80 = -1;
  if (use80 < 0) {
    hipError_t e = hipFuncSetAttribute(
        reinterpret_cast<const void*>(mega<80, 40>),
        hipFuncAttributeMaxDynamicSharedMemorySize, 80 * W * 4);
    use80 = (e == hipSuccess) ? 1 : 0;
    if (!use80) {
      (void)hipFuncSetAttribute(
          reinterpret_cast<const void*>(mega<64, 24>),
          hipFuncAttributeMaxDynamicSharedMemorySize, 64 * W * 4);
    }
  }

  zero_acc<<<1, 256, 0, stream>>>();
  if (use80) {
    constexpr int NSTRIP = (H + 39) / 40;          // 13
    mega<80, 40><<<128 * NSTRIP, 1024, 80 * W * 4, stream>>>(pred, target);
  } else {
    constexpr int NSTRIP = (H + 23) / 24;          // 22
    mega<64, 24><<<128 * NSTRIP, 1024, 64 * W * 4, stream>>>(pred, target);
  }
  final_kernel<<<1, 64, 0, stream>>>(out);
}